// Round 1
// baseline (634.785 us; speedup 1.0000x reference)
//
#include <hip/hip_runtime.h>

#define N_NODES 100000
#define N_EDGES 1600000
#define D 64

// One wave (64 lanes) per edge: lane i owns feature dim i.
// a = <h_src, h_dst> via wave shfl-xor reduction, then
// atomicAdd(neigh[dst*64+i], h_src[i]*a)  -- coalesced 256B per wave.
__global__ __launch_bounds__(256) void edge_kernel(
    const float* __restrict__ feat,
    const int* __restrict__ esrc,
    const int* __restrict__ edst,
    float* __restrict__ neigh)
{
    const int wave = (blockIdx.x * blockDim.x + threadIdx.x) >> 6;
    const int lane = threadIdx.x & 63;
    if (wave >= N_EDGES) return;

    const int s = esrc[wave];
    const int d = edst[wave];

    const float hs = feat[s * D + lane];
    const float hd = feat[d * D + lane];

    float p = hs * hd;
#pragma unroll
    for (int off = 32; off > 0; off >>= 1)
        p += __shfl_xor(p, off, 64);
    // p now holds a_e in all 64 lanes

    atomicAdd(&neigh[d * D + lane], hs * p);
}

// out[n,o] = sum_i neigh[n,i] * W[o,i]
// Block = 256 threads = 4 rows x 64 output-cols.
// W staged transposed in LDS: WT[i][o] -> lane-consecutive reads (2-way
// bank aliasing only, free). neigh row in LDS -> same-address broadcast.
__global__ __launch_bounds__(256) void gemm_kernel(
    const float* __restrict__ neigh,
    const float* __restrict__ W,
    float* __restrict__ out)
{
    __shared__ float WT[D][D];   // WT[i][o] = W[o*D+i]
    __shared__ float rows[4][D];

    const int tid = threadIdx.x;
#pragma unroll
    for (int idx = tid; idx < D * D; idx += 256) {
        const int o = idx >> 6;
        const int i = idx & 63;
        WT[i][o] = W[idx];
    }

    const int nl = tid >> 6;     // 0..3 local row
    const int o  = tid & 63;     // output column
    const int n  = blockIdx.x * 4 + nl;

    if (n < N_NODES) rows[nl][o] = neigh[n * D + o];
    __syncthreads();
    if (n >= N_NODES) return;

    float acc = 0.f;
#pragma unroll
    for (int i = 0; i < D; ++i)
        acc += rows[nl][i] * WT[i][o];

    out[n * D + o] = acc;
}

extern "C" void kernel_launch(void* const* d_in, const int* in_sizes, int n_in,
                              void* d_out, int out_size, void* d_ws, size_t ws_size,
                              hipStream_t stream) {
    const float* feat = (const float*)d_in[0];
    const int*   esrc = (const int*)d_in[1];
    const int*   edst = (const int*)d_in[2];
    const float* W    = (const float*)d_in[3];
    float* out   = (float*)d_out;
    float* neigh = (float*)d_ws;   // N_NODES * D floats = 25.6 MB

    hipMemsetAsync(neigh, 0, (size_t)N_NODES * D * sizeof(float), stream);

    // 4 edges (waves) per 256-thread block
    edge_kernel<<<(N_EDGES + 3) / 4, 256, 0, stream>>>(feat, esrc, edst, neigh);

    gemm_kernel<<<(N_NODES + 3) / 4, 256, 0, stream>>>(neigh, W, out);
}

// Round 2
// 369.959 us; speedup vs baseline: 1.7158x; 1.7158x over previous
//
#include <hip/hip_runtime.h>

#define N_NODES 100000
#define N_EDGES 1600000
#define D 64
#define SCAN_CHUNK 1024
#define NB_SCAN ((N_NODES + SCAN_CHUNK - 1) / SCAN_CHUNK)  // 98

// ---------- CSR build ----------

__global__ __launch_bounds__(256) void hist_kernel(const int* __restrict__ edst,
                                                   int* __restrict__ cnt) {
    int e = blockIdx.x * 256 + threadIdx.x;
    if (e < N_EDGES) atomicAdd(&cnt[edst[e]], 1);
}

// Per-1024-chunk exclusive scan; writes per-element exclusive prefix into
// cursor[] and the chunk total into bsums[blockIdx.x].
__global__ __launch_bounds__(256) void scan_a(const int* __restrict__ cnt,
                                              int* __restrict__ cursor,
                                              int* __restrict__ bsums) {
    __shared__ int s[256];
    const int t = threadIdx.x;
    const int base = blockIdx.x * SCAN_CHUNK + t * 4;
    int v0 = 0, v1 = 0, v2 = 0, v3 = 0;
    if (base + 0 < N_NODES) v0 = cnt[base + 0];
    if (base + 1 < N_NODES) v1 = cnt[base + 1];
    if (base + 2 < N_NODES) v2 = cnt[base + 2];
    if (base + 3 < N_NODES) v3 = cnt[base + 3];
    const int sum = v0 + v1 + v2 + v3;
    s[t] = sum;
    __syncthreads();
    for (int off = 1; off < 256; off <<= 1) {
        int x = (t >= off) ? s[t - off] : 0;
        __syncthreads();
        s[t] += x;
        __syncthreads();
    }
    int run = s[t] - sum;  // exclusive prefix of this thread's chunk
    if (base + 0 < N_NODES) cursor[base + 0] = run;
    run += v0;
    if (base + 1 < N_NODES) cursor[base + 1] = run;
    run += v1;
    if (base + 2 < N_NODES) cursor[base + 2] = run;
    run += v2;
    if (base + 3 < N_NODES) cursor[base + 3] = run;
    if (t == 255) bsums[blockIdx.x] = s[255];
}

__global__ void scan_b(int* bsums) {  // 1 block, 128 threads
    __shared__ int s[128];
    const int t = threadIdx.x;
    const int v = (t < NB_SCAN) ? bsums[t] : 0;
    s[t] = v;
    __syncthreads();
    for (int off = 1; off < 128; off <<= 1) {
        int x = (t >= off) ? s[t - off] : 0;
        __syncthreads();
        s[t] += x;
        __syncthreads();
    }
    if (t < NB_SCAN) bsums[t] = s[t] - v;  // exclusive
}

__global__ __launch_bounds__(256) void scan_c(int* __restrict__ cursor,
                                              const int* __restrict__ bsums) {
    int i = blockIdx.x * 256 + threadIdx.x;
    if (i < N_NODES) cursor[i] += bsums[i >> 10];
}

// cursor[v] = start offset of v; after this kernel cursor[v] = end offset of v.
__global__ __launch_bounds__(256) void scatter_kernel(const int* __restrict__ esrc,
                                                      const int* __restrict__ edst,
                                                      int* __restrict__ cursor,
                                                      int* __restrict__ srt) {
    int e = blockIdx.x * 256 + threadIdx.x;
    if (e < N_EDGES) {
        int d = edst[e];
        int pos = atomicAdd(&cursor[d], 1);
        srt[pos] = esrc[e];
    }
}

// ---------- fused SDDMM + SpMM ----------
// 4 node-slots per wave, 16 lanes/slot, one float4 (4 feature dims) per lane.
// Per edge: coalesced 256B gather of feat[src], 4-step shfl-xor dot-reduce
// (stays inside the 16-lane slot), register accumulate. One plain store per
// node at the end -- NO atomics. Writes neigh into d_out.
__global__ __launch_bounds__(256) void spmm_kernel(const float4* __restrict__ feat4,
                                                   const int* __restrict__ cursor,
                                                   const int* __restrict__ srt,
                                                   float4* __restrict__ neigh4) {
    const int t = threadIdx.x;
    const int slot = t >> 4;              // 0..15 in block
    const int l = t & 15;
    const int v = blockIdx.x * 16 + slot; // grid sized so v < N_NODES exactly
    const float4 hd = feat4[v * 16 + l];
    const int start = (v == 0) ? 0 : cursor[v - 1];
    const int end = cursor[v];            // post-scatter cursor = end offsets
    float ax = 0.f, ay = 0.f, az = 0.f, aw = 0.f;
    int e = start;
    int u = (e < end) ? srt[e] : 0;
    while (e < end) {
        const int un = (e + 1 < end) ? srt[e + 1] : 0;  // prefetch next src idx
        const float4 hs = feat4[u * 16 + l];
        float p = hs.x * hd.x + hs.y * hd.y + hs.z * hd.z + hs.w * hd.w;
        p += __shfl_xor(p, 8, 64);
        p += __shfl_xor(p, 4, 64);
        p += __shfl_xor(p, 2, 64);
        p += __shfl_xor(p, 1, 64);        // p = a_e, broadcast in slot
        ax += hs.x * p;
        ay += hs.y * p;
        az += hs.z * p;
        aw += hs.w * p;
        u = un;
        ++e;
    }
    neigh4[v * 16 + l] = make_float4(ax, ay, az, aw);
}

// ---------- in-place GEMM: out[n,:] = out[n,:] @ W^T ----------
// 128-row tile per block; thread computes 8 rows x 4 cols (32 FMAs per
// 3 ds_read_b128). Tile staged transposed in LDS, so the block can safely
// overwrite its own global rows afterwards (no other block touches them).
__global__ __launch_bounds__(256) void gemm_inplace(float* __restrict__ out,
                                                    const float* __restrict__ W) {
    __shared__ float WT[64][68];    // WT[i][o] = W[o][i]; stride 68 keeps 16B align
    __shared__ float nT[64][132];   // nT[i][r] = tile[r][i]
    const int t = threadIdx.x;

    const float4* W4 = (const float4*)W;
#pragma unroll
    for (int j = 0; j < 4; ++j) {
        int f = t + j * 256;        // 0..1023 float4s of W
        int o = f >> 4;
        int i4 = (f & 15) * 4;
        float4 w = W4[f];
        WT[i4 + 0][o] = w.x;
        WT[i4 + 1][o] = w.y;
        WT[i4 + 2][o] = w.z;
        WT[i4 + 3][o] = w.w;
    }

    const int base = blockIdx.x * 128;
    const int rows = min(128, N_NODES - base);
    const float4* O4 = (const float4*)(out + (long)base * D);
#pragma unroll
    for (int j = 0; j < 8; ++j) {
        int f = t + j * 256;        // 0..2047 float4s of the tile
        int r = f >> 4;
        int i4 = (f & 15) * 4;
        if (r < rows) {
            float4 x = O4[f];
            nT[i4 + 0][r] = x.x;
            nT[i4 + 1][r] = x.y;
            nT[i4 + 2][r] = x.z;
            nT[i4 + 3][r] = x.w;
        }
    }
    __syncthreads();

    const int c4 = (t & 15) * 4;
    const int r0 = (t >> 4) * 8;
    float acc[8][4];
#pragma unroll
    for (int r = 0; r < 8; ++r)
#pragma unroll
        for (int c = 0; c < 4; ++c) acc[r][c] = 0.f;

    for (int i = 0; i < 64; ++i) {
        const float4 w = *(const float4*)&WT[i][c4];
        const float4 ra = *(const float4*)&nT[i][r0];
        const float4 rb = *(const float4*)&nT[i][r0 + 4];
        const float wv[4] = {w.x, w.y, w.z, w.w};
        const float rv[8] = {ra.x, ra.y, ra.z, ra.w, rb.x, rb.y, rb.z, rb.w};
#pragma unroll
        for (int r = 0; r < 8; ++r)
#pragma unroll
            for (int c = 0; c < 4; ++c) acc[r][c] += rv[r] * wv[c];
    }

#pragma unroll
    for (int r = 0; r < 8; ++r) {
        int rr = r0 + r;
        if (rr < rows)
            *(float4*)&out[(long)(base + rr) * D + c4] =
                make_float4(acc[r][0], acc[r][1], acc[r][2], acc[r][3]);
    }
}

extern "C" void kernel_launch(void* const* d_in, const int* in_sizes, int n_in,
                              void* d_out, int out_size, void* d_ws, size_t ws_size,
                              hipStream_t stream) {
    const float* feat = (const float*)d_in[0];
    const int*   esrc = (const int*)d_in[1];
    const int*   edst = (const int*)d_in[2];
    const float* W    = (const float*)d_in[3];
    float* out = (float*)d_out;

    char* ws = (char*)d_ws;
    int* cnt    = (int*)(ws);                 // 400,000 B
    int* cursor = (int*)(ws + 400000);        // 400,000 B
    int* bsums  = (int*)(ws + 800000);        // 2,048 B (98 used)
    int* srt    = (int*)(ws + 802048);        // 6.4 MB

    hipMemsetAsync(cnt, 0, N_NODES * sizeof(int), stream);
    hist_kernel<<<(N_EDGES + 255) / 256, 256, 0, stream>>>(edst, cnt);
    scan_a<<<NB_SCAN, 256, 0, stream>>>(cnt, cursor, bsums);
    scan_b<<<1, 128, 0, stream>>>(bsums);
    scan_c<<<(N_NODES + 255) / 256, 256, 0, stream>>>(cursor, bsums);
    scatter_kernel<<<(N_EDGES + 255) / 256, 256, 0, stream>>>(esrc, edst, cursor, srt);
    spmm_kernel<<<N_NODES / 16, 256, 0, stream>>>((const float4*)feat, cursor, srt,
                                                  (float4*)out);
    gemm_inplace<<<(N_NODES + 127) / 128, 256, 0, stream>>>(out, W);
}